// Round 3
// baseline (95.682 us; speedup 1.0000x reference)
//
#include <hip/hip_runtime.h>
#include <hip/hip_bf16.h>
#include <hip/hip_cooperative_groups.h>

namespace cg = cooperative_groups;

#define NB   16     // B
#define NN   512    // MAX_N
#define NE   1024   // MAX_E
#define NBETA 64    // MAX_BETA
#define NHID 128
#define NTILE (NB * 32)   // 512 tiles of 32 edges

typedef __attribute__((ext_vector_type(8))) short short8;
typedef __attribute__((ext_vector_type(4))) float f32x4;

static __device__ __forceinline__ unsigned short f2bf(float f) {
    unsigned u = __float_as_uint(f);
    return (unsigned short)((u + 0x7fffu + ((u >> 16) & 1u)) >> 16);   // RNE
}

static __device__ __forceinline__ f32x4 splat4(float v) {
    f32x4 r; r.x = v; r.y = v; r.z = v; r.w = v; return r;
}

// ---------------------------------------------------------------------------
// One kernel, three launch modes (phase):
//   0 : cooperative, 256 blocks — phase1 ; grid.sync ; phase2 (work-steal)
//   1 : regular fallback, 256 blocks — phase1 only (+ ctr reset at end)
//   2 : regular fallback, 512 blocks — phase2 only
// Phase 1 (grid must be 256): 4 (b,beta) tasks/block (128 thr, shfl-reduce)
//   -> base[]; 192 weight elems/block -> bf16 swizzled wsT[].
// Phase 2: 32-edge fused tiles pulled from device-scope atomic ctr (dynamic
//   balance of el/bl imbalance). Padded tiles zero-store and continue.
//   Per tile: phase E (VALU) + 3 bf16 MFMA layers, weights register-
//   prefetched and committed to LDS post-barrier.
// Workspace: base 512 KB | wsT 96 KB | ctr 4 B.
// ---------------------------------------------------------------------------
__global__ __launch_bounds__(512) void k_all(
        const float* __restrict__ x, const int* __restrict__ ei,
        const float* __restrict__ SCB,
        const int* __restrict__ elen, const int* __restrict__ blen,
        const float* __restrict__ W1, const float* __restrict__ b1,
        const float* __restrict__ W2, const float* __restrict__ b2,
        const float* __restrict__ W3, const float* __restrict__ b3,
        const float* __restrict__ W4, const float* __restrict__ b4,
        const float* __restrict__ W5, const float* __restrict__ b5,
        const float* __restrict__ W6, const float* __restrict__ b6,
        float* __restrict__ base, unsigned short* __restrict__ wsT,
        unsigned int* __restrict__ ctr, float* __restrict__ out, int phase) {
    __shared__ __align__(16) char lds[65536];
    int bid = blockIdx.x, tid = threadIdx.x;

    if (phase != 2) {
        // ------------- Phase 1a: weight transform (192 elems/block) --------
        if (tid < 192) {
            int j = bid * 192 + tid;                  // 0..49151
            int w = j >> 14, rem = j & 16383;
            int k = rem & 127, n = rem >> 7;
            const float* W = (w == 0) ? W4 : ((w == 1) ? W5 : W6);
            float v = W[k * NHID + n];
            int byte = n * 256 + ((2 * k) ^ ((n & 7) << 4));
            *reinterpret_cast<unsigned short*>(
                reinterpret_cast<char*>(wsT) + (size_t)w * 32768 + byte) = f2bf(v);
        }
        // ------------- Phase 1b: four (b,beta) tasks per block -------------
        {
            int hf = tid >> 7, t = tid & 127;         // task, lane-in-task
            int bb = bid * 4 + hf;                    // 0..1023
            int b = bb >> 6, beta = bb & 63;
            int el = elen[b], bl = blen[b];
            float a0 = 0, a1 = 0, a2 = 0, a3 = 0;
            if (beta < bl) {
                const float* row = SCB + (size_t)bb * NE;
                const int* eis = ei + b * 2 * NE;
                const float* xb = x + b * NN * 2;
                for (int e = t; e < el; e += 128) {
                    float tt = fabsf(row[e]);
                    int s0 = eis[e], s1 = eis[NE + e];
                    float2 v0 = *reinterpret_cast<const float2*>(xb + 2 * s0);
                    float2 v1 = *reinterpret_cast<const float2*>(xb + 2 * s1);
                    a0 = fmaf(tt, v0.x, a0);
                    a1 = fmaf(tt, v0.y, a1);
                    a2 = fmaf(tt, v1.x, a2);
                    a3 = fmaf(tt, v1.y, a3);
                }
            }
            #pragma unroll
            for (int off = 32; off > 0; off >>= 1) {  // wave64 butterfly
                a0 += __shfl_down(a0, off);
                a1 += __shfl_down(a1, off);
                a2 += __shfl_down(a2, off);
                a3 += __shfl_down(a3, off);
            }
            float* part = reinterpret_cast<float*>(lds);          // [8 waves][4]
            if ((tid & 63) == 0) {
                int w8 = tid >> 6;
                part[w8 * 4 + 0] = a0; part[w8 * 4 + 1] = a1;
                part[w8 * 4 + 2] = a2; part[w8 * 4 + 3] = a3;
            }
            __syncthreads();
            float* h1s  = reinterpret_cast<float*>(lds + 128);    // [4][64]
            float* embs = reinterpret_cast<float*>(lds + 1152);   // [4][64]
            if (t < 64) {
                float v = b1[t];
                #pragma unroll
                for (int i = 0; i < 4; ++i) {
                    float si = part[(2 * hf) * 4 + i] + part[(2 * hf + 1) * 4 + i];
                    v = fmaf(si, W1[i * 64 + t], v);
                }
                h1s[hf * 64 + t] = fmaxf(v, 0.f);
            }
            __syncthreads();
            if (t < 64) {
                float v = b2[t];
                #pragma unroll 8
                for (int k = 0; k < 64; ++k)
                    v = fmaf(h1s[hf * 64 + k], W2[k * 64 + t], v);
                embs[hf * 64 + t] = v;
            }
            __syncthreads();
            {
                float v = b3[t];
                #pragma unroll 8
                for (int k = 0; k < 64; ++k)
                    v = fmaf(embs[hf * 64 + k], W3[k * NHID + t], v);
                base[(size_t)bb * NHID + t] = v;
            }
        }
        if (bid == 0 && tid == 0) atomicExch(ctr, 0u);   // device-scope reset
        if (phase == 1) return;
        __threadfence();
        cg::this_grid().sync();
    }

    // ---------------- Phase 2: fused 32-edge tiles, work-stealing ----------
    float* baseS = reinterpret_cast<float*>(lds);             // 32K (phase E)
    char*  wS    = lds + 32768;                               // 32K
    float4* efS  = reinterpret_cast<float4*>(wS);             // 512 B
    float* w3r   = reinterpret_cast<float*>(wS + 512);        // 2 K
    float* tS    = reinterpret_cast<float*>(wS + 8192);       // 8 K [beta][32]
    unsigned int* tileS = reinterpret_cast<unsigned int*>(lds + 32768 + 2560);
    char* io0 = lds;                                          // 8K A / L5 out
    char* io1 = lds + 8192;                                   // 8K L4 out

    const float4* w4src = reinterpret_cast<const float4*>(wsT);
    const float4* w5src = reinterpret_cast<const float4*>(
        reinterpret_cast<const char*>(wsT) + 32768);
    const float4* w6src = reinterpret_cast<const float4*>(
        reinterpret_cast<const char*>(wsT) + 65536);

    while (true) {
        __syncthreads();                     // prior tile's LDS readers done
        if (tid == 0) *tileS = atomicAdd(ctr, 1u);
        __syncthreads();
        unsigned int tile = *tileS;          // read before stage writes lds
        if (tile >= NTILE) break;
        int b = (int)tile >> 5;
        int e0 = ((int)tile & 31) * 32;
        int el = elen[b];
        if (e0 >= el) {                      // fully-padded: zero, next tile
            float4 z; z.x = 0.f; z.y = 0.f; z.z = 0.f; z.w = 0.f;
            float4* o4 = reinterpret_cast<float4*>(out) + (size_t)(b * NE + e0) * 32;
            o4[tid] = z;
            o4[tid + 512] = z;
            continue;
        }
        int bl = blen[b];
        float4 pw0, pw1, pw2, pw3;           // in-flight weight tile

        {   // stage (base, |SCB| tile, edge feats, W3 rows 64..67) + W4 prefetch
            const float4* bsrc = reinterpret_cast<const float4*>(
                base + (size_t)b * NBETA * NHID);
            float4* bd = reinterpret_cast<float4*>(baseS);
            #pragma unroll
            for (int i = 0; i < 4; ++i) bd[tid + 512 * i] = bsrc[tid + 512 * i];
            {
                int row = tid >> 3, c4 = tid & 7;
                float4 v = *reinterpret_cast<const float4*>(
                    SCB + (size_t)(b * NBETA + row) * NE + e0 + c4 * 4);
                v.x = fabsf(v.x); v.y = fabsf(v.y); v.z = fabsf(v.z); v.w = fabsf(v.w);
                reinterpret_cast<float4*>(tS)[tid] = v;
            }
            if (tid < 64) {
                int e = tid >> 1, hf2 = tid & 1;
                int idx = ei[b * 2 * NE + hf2 * NE + e0 + e];
                float2 v2 = *reinterpret_cast<const float2*>(x + b * NN * 2 + idx * 2);
                reinterpret_cast<float2*>(&efS[e])[hf2] = v2;
            }
            w3r[tid] = W3[64 * NHID + tid];
            pw0 = w4src[tid];        pw1 = w4src[tid + 512];
            pw2 = w4src[tid + 1024]; pw3 = w4src[tid + 1536];
        }
        __syncthreads();

        // ---------------- Phase E ----------------
        int cg2 = tid & 31, es = tid >> 5;   // channel group; edges es*2+j
        f32x4 w0  = reinterpret_cast<const f32x4*>(w3r)[cg2];
        f32x4 w1  = reinterpret_cast<const f32x4*>(w3r)[32 + cg2];
        f32x4 w2  = reinterpret_cast<const f32x4*>(w3r)[64 + cg2];
        f32x4 w3v = reinterpret_cast<const f32x4*>(w3r)[96 + cg2];
        f32x4 gv[2], acc[2];
        #pragma unroll
        for (int j = 0; j < 2; ++j) {
            float4 e4 = efS[es * 2 + j];
            f32x4 g = w3v * splat4(e4.w);
            g = __builtin_elementwise_fma(splat4(e4.z), w2, g);
            g = __builtin_elementwise_fma(splat4(e4.y), w1, g);
            g = __builtin_elementwise_fma(splat4(e4.x), w0, g);
            gv[j] = g;
            acc[j] = splat4(0.f);
        }
        const f32x4* base4 = reinterpret_cast<const f32x4*>(baseS);
        const f32x4 zero = splat4(0.f);
        for (int beta = 0; beta < bl; ++beta) {
            f32x4 bs = base4[beta * 32 + cg2];
            float2 tv = *reinterpret_cast<const float2*>(tS + beta * 32 + es * 2);
            acc[0] += __builtin_elementwise_max(
                __builtin_elementwise_fma(splat4(tv.x), gv[0], bs), zero);
            acc[1] += __builtin_elementwise_max(
                __builtin_elementwise_fma(splat4(tv.y), gv[1], bs), zero);
        }
        if (bl < NBETA) {
            f32x4 bp = base4[bl * 32 + cg2];          // padded row == base_pad
            f32x4 r = __builtin_elementwise_max(bp, zero);
            f32x4 fcv = splat4((float)(NBETA - bl));
            acc[0] = __builtin_elementwise_fma(fcv, r, acc[0]);
            acc[1] = __builtin_elementwise_fma(fcv, r, acc[1]);
        }
        __syncthreads();   // S1: baseS/tS/efS/w3r dead

        // A-tile (bf16, XOR-swizzled) into io0; commit W4; prefetch W5
        #pragma unroll
        for (int j = 0; j < 2; ++j) {
            int rl = es * 2 + j;
            int byte = rl * 256 + ((cg2 * 8) ^ ((rl & 7) << 4));
            ushort4 u;
            u.x = f2bf(acc[j].x); u.y = f2bf(acc[j].y);
            u.z = f2bf(acc[j].z); u.w = f2bf(acc[j].w);
            *reinterpret_cast<ushort4*>(io0 + byte) = u;
        }
        float4* wd = reinterpret_cast<float4*>(wS);
        wd[tid] = pw0; wd[tid + 512] = pw1; wd[tid + 1024] = pw2; wd[tid + 1536] = pw3;
        pw0 = w5src[tid];        pw1 = w5src[tid + 512];
        pw2 = w5src[tid + 1024]; pw3 = w5src[tid + 1536];
        __syncthreads();   // S2: A + W4 visible

        // ------------- Phase F: 3-layer bf16 MFMA GEMM (32x128 @ 128x128) --
        int l = tid & 63, wid = tid >> 6;
        int wm = wid & 1, wn = wid >> 1;     // 2M x 4N waves over 32x128
        const int lrow = l & 15;
        const int kbl = (l >> 4) * 16;

        auto layerc = [&](const char* ioIn, char* ioOut, const float* bias,
                          float bscale, bool doRelu, bool final_) {
            f32x4 facc[2];
            facc[0] = splat4(0.f); facc[1] = splat4(0.f);
            int rowA = wm * 16 + lrow;
            #pragma unroll
            for (int ks = 0; ks < 4; ++ks) {
                int kbyte = ks * 64 + kbl;
                short8 a = *reinterpret_cast<const short8*>(
                    ioIn + rowA * 256 + (kbyte ^ ((rowA & 7) << 4)));
                #pragma unroll
                for (int nf = 0; nf < 2; ++nf) {
                    int col = wn * 32 + nf * 16 + lrow;
                    short8 bf = *reinterpret_cast<const short8*>(
                        wS + col * 256 + (kbyte ^ ((col & 7) << 4)));
                    facc[nf] = __builtin_amdgcn_mfma_f32_16x16x32_bf16(a, bf, facc[nf], 0, 0, 0);
                }
            }
            #pragma unroll
            for (int nf = 0; nf < 2; ++nf) {
                int colg = wn * 32 + nf * 16 + lrow;
                float bvv = bias[colg];
                #pragma unroll
                for (int r = 0; r < 4; ++r) {
                    int row = wm * 16 + (l >> 4) * 4 + r;
                    float v = fmaf(bscale, bvv, facc[nf][r]);
                    if (doRelu) v = fmaxf(v, 0.f);
                    if (!final_) {
                        *reinterpret_cast<unsigned short*>(
                            ioOut + row * 256 + ((colg * 2) ^ ((row & 7) << 4))) = f2bf(v);
                    } else {
                        int eg = e0 + row;
                        float vv = (eg >= el) ? 0.f : v;
                        out[(size_t)(b * NE + eg) * NHID + colg] = vv;
                    }
                }
            }
        };

        layerc(io0, io1, b4, 64.f, false, false);      // h = hacc@W4 + 64*b4
        __syncthreads();   // S3: W4/io0 reads done
        wd[tid] = pw0; wd[tid + 512] = pw1; wd[tid + 1024] = pw2; wd[tid + 1536] = pw3;
        pw0 = w6src[tid];        pw1 = w6src[tid + 512];
        pw2 = w6src[tid + 1024]; pw3 = w6src[tid + 1536];
        __syncthreads();   // S4: W5 visible
        layerc(io1, io0, b5, 1.f, true, false);        // u = relu(h@W5 + b5)
        __syncthreads();   // S5: W5/io1 reads done
        wd[tid] = pw0; wd[tid + 512] = pw1; wd[tid + 1024] = pw2; wd[tid + 1536] = pw3;
        __syncthreads();   // S6: W6 visible
        layerc(io0, nullptr, b6, 1.f, false, true);    // out = u@W6 + b6
    }
}

extern "C" void kernel_launch(void* const* d_in, const int* in_sizes, int n_in,
                              void* d_out, int out_size, void* d_ws, size_t ws_size,
                              hipStream_t stream) {
    const float* x    = (const float*)d_in[0];
    const float* SCB  = (const float*)d_in[1];
    const int*   ei   = (const int*)d_in[2];
    const int*   elen = (const int*)d_in[3];
    const int*   blen = (const int*)d_in[4];
    const float* W1 = (const float*)d_in[5];  const float* b1 = (const float*)d_in[6];
    const float* W2 = (const float*)d_in[7];  const float* b2 = (const float*)d_in[8];
    const float* W3 = (const float*)d_in[9];  const float* b3 = (const float*)d_in[10];
    const float* W4 = (const float*)d_in[11]; const float* b4 = (const float*)d_in[12];
    const float* W5 = (const float*)d_in[13]; const float* b5 = (const float*)d_in[14];
    const float* W6 = (const float*)d_in[15]; const float* b6 = (const float*)d_in[16];
    float* out = (float*)d_out;

    float* ws = (float*)d_ws;
    float* base = ws;                                                   // 131072 f
    unsigned short* wsT = (unsigned short*)(base + NB * NBETA * NHID);  // 49152 bf16
    unsigned int* ctr = (unsigned int*)(wsT + 49152);                   // 4 B

    int ph0 = 0;
    void* args[] = { (void*)&x, (void*)&ei, (void*)&SCB, (void*)&elen, (void*)&blen,
                     (void*)&W1, (void*)&b1, (void*)&W2, (void*)&b2,
                     (void*)&W3, (void*)&b3, (void*)&W4, (void*)&b4,
                     (void*)&W5, (void*)&b5, (void*)&W6, (void*)&b6,
                     (void*)&base, (void*)&wsT, (void*)&ctr, (void*)&out,
                     (void*)&ph0 };
    hipError_t err = hipLaunchCooperativeKernel((const void*)k_all, dim3(256),
                                                dim3(512), args, 0, stream);
    if (err != hipSuccess) {
        (void)hipGetLastError();   // clear sticky error; use 2-dispatch fallback
        hipLaunchKernelGGL(k_all, dim3(256), dim3(512), 0, stream,
                           x, ei, SCB, elen, blen, W1, b1, W2, b2, W3, b3,
                           W4, b4, W5, b5, W6, b6, base, wsT, ctr, out, 1);
        hipLaunchKernelGGL(k_all, dim3(512), dim3(512), 0, stream,
                           x, ei, SCB, elen, blen, W1, b1, W2, b2, W3, b3,
                           W4, b4, W5, b5, W6, b6, base, wsT, ctr, out, 2);
    }
}

// Round 4
// 26.962 us; speedup vs baseline: 3.5488x; 3.5488x over previous
//
#include <hip/hip_runtime.h>
#include <hip/hip_bf16.h>

#define NB   16     // B
#define NN   512    // MAX_N
#define NE   1024   // MAX_E
#define NBETA 64    // MAX_BETA
#define NHID 128

typedef __attribute__((ext_vector_type(8))) short short8;
typedef __attribute__((ext_vector_type(4))) float f32x4;

static __device__ __forceinline__ unsigned short f2bf(float f) {
    unsigned u = __float_as_uint(f);
    return (unsigned short)((u + 0x7fffu + ((u >> 16) & 1u)) >> 16);   // RNE
}

static __device__ __forceinline__ f32x4 splat4(float v) {
    f32x4 r; r.x = v; r.y = v; r.z = v; r.w = v; return r;
}

// ---------------------------------------------------------------------------
// Workspace (floats): base = NB*NBETA*128 (512 KB); wsT = 3*128*128 bf16 (96 KB)
// ---------------------------------------------------------------------------

// Kernel 1 (256 blocks x 512): four (b,beta) tasks/block (128 thr each,
//   wave-shfl butterfly reduce — no LDS tree, 3 barriers total) -> base[];
//   plus 192 weight elems/block -> bf16 transposed + XOR-swizzled wsT[].
__global__ __launch_bounds__(512) void k_base_wt(
        const float* __restrict__ x, const int* __restrict__ ei,
        const float* __restrict__ SCB,
        const int* __restrict__ elen, const int* __restrict__ blen,
        const float* __restrict__ W1, const float* __restrict__ b1,
        const float* __restrict__ W2, const float* __restrict__ b2,
        const float* __restrict__ W3, const float* __restrict__ b3,
        const float* __restrict__ W4, const float* __restrict__ W5,
        const float* __restrict__ W6,
        float* __restrict__ base, unsigned short* __restrict__ wsT) {
    __shared__ float part[32];        // [8 waves][4]
    __shared__ float h1s[4][64];
    __shared__ float embs[4][64];
    int bid = blockIdx.x, tid = threadIdx.x;

    // --- weight transform: 192 elems/block (256*192 = 49152 total) ---
    if (tid < 192) {
        int j = bid * 192 + tid;
        int w = j >> 14, rem = j & 16383;
        int k = rem & 127, n = rem >> 7;
        const float* W = (w == 0) ? W4 : ((w == 1) ? W5 : W6);
        float v = W[k * NHID + n];
        int byte = n * 256 + ((2 * k) ^ ((n & 7) << 4));
        *reinterpret_cast<unsigned short*>(
            reinterpret_cast<char*>(wsT) + (size_t)w * 32768 + byte) = f2bf(v);
    }

    // --- four (b,beta) tasks per block ---
    int hf = tid >> 7, t = tid & 127;             // task, lane-in-task
    int bb = bid * 4 + hf;                        // 0..1023
    int b = bb >> 6, beta = bb & 63;
    int el = elen[b], bl = blen[b];
    float a0 = 0, a1 = 0, a2 = 0, a3 = 0;
    if (beta < bl) {
        const float* row = SCB + (size_t)bb * NE;
        const int* eis = ei + b * 2 * NE;
        const float* xb = x + b * NN * 2;
        for (int e = t; e < el; e += 128) {
            float tt = fabsf(row[e]);
            int s0 = eis[e], s1 = eis[NE + e];
            float2 v0 = *reinterpret_cast<const float2*>(xb + 2 * s0);
            float2 v1 = *reinterpret_cast<const float2*>(xb + 2 * s1);
            a0 = fmaf(tt, v0.x, a0);
            a1 = fmaf(tt, v0.y, a1);
            a2 = fmaf(tt, v1.x, a2);
            a3 = fmaf(tt, v1.y, a3);
        }
    }
    #pragma unroll
    for (int off = 32; off > 0; off >>= 1) {      // wave64 butterfly
        a0 += __shfl_down(a0, off);
        a1 += __shfl_down(a1, off);
        a2 += __shfl_down(a2, off);
        a3 += __shfl_down(a3, off);
    }
    if ((tid & 63) == 0) {
        int w8 = tid >> 6;
        part[w8 * 4 + 0] = a0; part[w8 * 4 + 1] = a1;
        part[w8 * 4 + 2] = a2; part[w8 * 4 + 3] = a3;
    }
    __syncthreads();
    if (t < 64) {
        float v = b1[t];
        #pragma unroll
        for (int i = 0; i < 4; ++i) {
            float si = part[(2 * hf) * 4 + i] + part[(2 * hf + 1) * 4 + i];
            v = fmaf(si, W1[i * 64 + t], v);
        }
        h1s[hf][t] = fmaxf(v, 0.f);
    }
    __syncthreads();
    if (t < 64) {
        float v = b2[t];
        #pragma unroll 8
        for (int k = 0; k < 64; ++k) v = fmaf(h1s[hf][k], W2[k * 64 + t], v);
        embs[hf][t] = v;
    }
    __syncthreads();
    {
        float v = b3[t];
        #pragma unroll 8
        for (int k = 0; k < 64; ++k) v = fmaf(embs[hf][k], W3[k * NHID + t], v);
        base[(size_t)bb * NHID + t] = v;
    }
}

// Kernel 2 (512 blocks x 512): per 32-edge tile.  b = bid & 15 interleave:
//   consecutive blocks (which co-schedule 2-per-CU) come from different
//   batches -> heavy-bl tiles spread across CUs instead of bunching.
//   Padded tiles (e0 >= el) zero-store and exit.  W4/W5/W6 register-
//   prefetched, committed to LDS post-barrier (no serial global stalls).
__global__ __launch_bounds__(512) void k_fused(
        const float* __restrict__ x, const int* __restrict__ ei,
        const float* __restrict__ SCB,
        const int* __restrict__ elen, const int* __restrict__ blen,
        const float* __restrict__ W3,
        const float* __restrict__ base, const unsigned short* __restrict__ wsT,
        const float* __restrict__ b4, const float* __restrict__ b5,
        const float* __restrict__ b6,
        float* __restrict__ out) {
    int bid = blockIdx.x, tid = threadIdx.x;
    int b = bid & 15;
    int e0 = (bid >> 4) * 32;
    int el = elen[b];
    if (e0 >= el) {                       // fully-padded tile: zero and leave
        float4 z; z.x = 0.f; z.y = 0.f; z.z = 0.f; z.w = 0.f;
        float4* o4 = reinterpret_cast<float4*>(out) + (size_t)(b * NE + e0) * (NHID / 4);
        o4[tid] = z;
        o4[tid + 512] = z;
        return;
    }
    int bl = blen[b];

    __shared__ __align__(16) char lds[65536];
    float* baseS = reinterpret_cast<float*>(lds);             // 32K, dead after E
    char*  wS    = lds + 32768;                               // 32K
    float4* efS  = reinterpret_cast<float4*>(wS);             // 512 B
    float* w3r   = reinterpret_cast<float*>(wS + 512);        // 2 K
    float* tS    = reinterpret_cast<float*>(wS + 8192);       // 8 K [beta][32]
    char* io0 = lds;                                          // 8K A-tile / L5 out
    char* io1 = lds + 8192;                                   // 8K L4 out

    const float4* w4src = reinterpret_cast<const float4*>(wsT);
    const float4* w5src = reinterpret_cast<const float4*>(
        reinterpret_cast<const char*>(wsT) + 32768);
    const float4* w6src = reinterpret_cast<const float4*>(
        reinterpret_cast<const char*>(wsT) + 65536);
    float4 pw0, pw1, pw2, pw3;            // in-flight weight tile

    {   // stage (base, |SCB| tile, edge feats, W3 rows 64..67) + W4 prefetch
        const float4* bsrc = reinterpret_cast<const float4*>(base + (size_t)b * NBETA * NHID);
        float4* bd = reinterpret_cast<float4*>(baseS);
        #pragma unroll
        for (int i = 0; i < 4; ++i) bd[tid + 512 * i] = bsrc[tid + 512 * i];
        {
            int row = tid >> 3, c4 = tid & 7;
            float4 v = *reinterpret_cast<const float4*>(
                SCB + (size_t)(b * NBETA + row) * NE + e0 + c4 * 4);
            v.x = fabsf(v.x); v.y = fabsf(v.y); v.z = fabsf(v.z); v.w = fabsf(v.w);
            reinterpret_cast<float4*>(tS)[tid] = v;
        }
        if (tid < 64) {
            int e = tid >> 1, hf = tid & 1;
            int idx = ei[b * 2 * NE + hf * NE + e0 + e];
            float2 v2 = *reinterpret_cast<const float2*>(x + b * NN * 2 + idx * 2);
            reinterpret_cast<float2*>(&efS[e])[hf] = v2;
        }
        w3r[tid] = W3[64 * NHID + tid];
        pw0 = w4src[tid];        pw1 = w4src[tid + 512];     // issued last ->
        pw2 = w4src[tid + 1024]; pw3 = w4src[tid + 1536];    // stay in flight
    }
    __syncthreads();

    // ---------------- Phase E ----------------
    int cg = tid & 31, es = tid >> 5;       // cg: f32x4 channel group; edges es*2+j
    f32x4 w0  = reinterpret_cast<const f32x4*>(w3r)[cg];
    f32x4 w1  = reinterpret_cast<const f32x4*>(w3r)[32 + cg];
    f32x4 w2  = reinterpret_cast<const f32x4*>(w3r)[64 + cg];
    f32x4 w3v = reinterpret_cast<const f32x4*>(w3r)[96 + cg];
    f32x4 gv[2], acc[2];
    #pragma unroll
    for (int j = 0; j < 2; ++j) {
        float4 e4 = efS[es * 2 + j];
        f32x4 g = w3v * splat4(e4.w);
        g = __builtin_elementwise_fma(splat4(e4.z), w2, g);
        g = __builtin_elementwise_fma(splat4(e4.y), w1, g);
        g = __builtin_elementwise_fma(splat4(e4.x), w0, g);
        gv[j] = g;
        acc[j] = splat4(0.f);
    }
    const f32x4* base4 = reinterpret_cast<const f32x4*>(baseS);
    const f32x4 zero = splat4(0.f);
    for (int beta = 0; beta < bl; ++beta) {
        f32x4 bs = base4[beta * 32 + cg];
        float2 tv = *reinterpret_cast<const float2*>(tS + beta * 32 + es * 2);
        acc[0] += __builtin_elementwise_max(
            __builtin_elementwise_fma(splat4(tv.x), gv[0], bs), zero);
        acc[1] += __builtin_elementwise_max(
            __builtin_elementwise_fma(splat4(tv.y), gv[1], bs), zero);
    }
    if (bl < NBETA) {
        f32x4 bp = base4[bl * 32 + cg];              // any padded row == base_pad
        f32x4 r = __builtin_elementwise_max(bp, zero);
        f32x4 fcv = splat4((float)(NBETA - bl));
        acc[0] = __builtin_elementwise_fma(fcv, r, acc[0]);
        acc[1] = __builtin_elementwise_fma(fcv, r, acc[1]);
    }
    __syncthreads();   // S1: baseS/tS/efS/w3r all dead

    // A-tile (bf16, XOR-swizzled) into io0; commit W4; prefetch W5
    #pragma unroll
    for (int j = 0; j < 2; ++j) {
        int rl = es * 2 + j;
        int byte = rl * 256 + ((cg * 8) ^ ((rl & 7) << 4));
        ushort4 u;
        u.x = f2bf(acc[j].x); u.y = f2bf(acc[j].y);
        u.z = f2bf(acc[j].z); u.w = f2bf(acc[j].w);
        *reinterpret_cast<ushort4*>(io0 + byte) = u;
    }
    float4* wd = reinterpret_cast<float4*>(wS);
    wd[tid] = pw0; wd[tid + 512] = pw1; wd[tid + 1024] = pw2; wd[tid + 1536] = pw3;
    pw0 = w5src[tid];        pw1 = w5src[tid + 512];
    pw2 = w5src[tid + 1024]; pw3 = w5src[tid + 1536];
    __syncthreads();   // S2: A + W4 visible

    // ---------------- Phase F: 3-layer bf16 MFMA GEMM (32x128 @ 128x128) ----
    int l = tid & 63, wid = tid >> 6;
    int wm = wid & 1, wn = wid >> 1;           // 2M x 4N waves over 32x128
    const int lrow = l & 15;
    const int kbl = (l >> 4) * 16;             // byte offset of lane's 8 bf16

    auto layerc = [&](const char* ioIn, char* ioOut, const float* bias,
                      float bscale, bool doRelu, bool final_) {
        f32x4 facc[2];
        facc[0] = splat4(0.f); facc[1] = splat4(0.f);
        int rowA = wm * 16 + lrow;
        #pragma unroll
        for (int ks = 0; ks < 4; ++ks) {
            int kbyte = ks * 64 + kbl;
            short8 a = *reinterpret_cast<const short8*>(
                ioIn + rowA * 256 + (kbyte ^ ((rowA & 7) << 4)));
            #pragma unroll
            for (int nf = 0; nf < 2; ++nf) {
                int col = wn * 32 + nf * 16 + lrow;
                short8 bf = *reinterpret_cast<const short8*>(
                    wS + col * 256 + (kbyte ^ ((col & 7) << 4)));
                facc[nf] = __builtin_amdgcn_mfma_f32_16x16x32_bf16(a, bf, facc[nf], 0, 0, 0);
            }
        }
        #pragma unroll
        for (int nf = 0; nf < 2; ++nf) {
            int colg = wn * 32 + nf * 16 + lrow;
            float bvv = bias[colg];
            #pragma unroll
            for (int r = 0; r < 4; ++r) {
                int row = wm * 16 + (l >> 4) * 4 + r;
                float v = fmaf(bscale, bvv, facc[nf][r]);
                if (doRelu) v = fmaxf(v, 0.f);
                if (!final_) {
                    *reinterpret_cast<unsigned short*>(
                        ioOut + row * 256 + ((colg * 2) ^ ((row & 7) << 4))) = f2bf(v);
                } else {
                    int eg = e0 + row;
                    float vv = (eg >= el) ? 0.f : v;
                    out[(size_t)(b * NE + eg) * NHID + colg] = vv;
                }
            }
        }
    };

    layerc(io0, io1, b4, 64.f, false, false);      // h = hacc@W4 + 64*b4
    __syncthreads();   // S3: W4/io0 reads done
    wd[tid] = pw0; wd[tid + 512] = pw1; wd[tid + 1024] = pw2; wd[tid + 1536] = pw3;
    pw0 = w6src[tid];        pw1 = w6src[tid + 512];
    pw2 = w6src[tid + 1024]; pw3 = w6src[tid + 1536];
    __syncthreads();   // S4: W5 visible
    layerc(io1, io0, b5, 1.f, true, false);        // u = relu(h@W5 + b5)
    __syncthreads();   // S5: W5/io1 reads done
    wd[tid] = pw0; wd[tid + 512] = pw1; wd[tid + 1024] = pw2; wd[tid + 1536] = pw3;
    __syncthreads();   // S6: W6 visible
    layerc(io0, nullptr, b6, 1.f, false, true);    // out = u@W6 + b6 (masked)
}

extern "C" void kernel_launch(void* const* d_in, const int* in_sizes, int n_in,
                              void* d_out, int out_size, void* d_ws, size_t ws_size,
                              hipStream_t stream) {
    const float* x    = (const float*)d_in[0];
    const float* SCB  = (const float*)d_in[1];
    const int*   ei   = (const int*)d_in[2];
    const int*   elen = (const int*)d_in[3];
    const int*   blen = (const int*)d_in[4];
    const float* W1 = (const float*)d_in[5];  const float* b1 = (const float*)d_in[6];
    const float* W2 = (const float*)d_in[7];  const float* b2 = (const float*)d_in[8];
    const float* W3 = (const float*)d_in[9];  const float* b3 = (const float*)d_in[10];
    const float* W4 = (const float*)d_in[11]; const float* b4 = (const float*)d_in[12];
    const float* W5 = (const float*)d_in[13]; const float* b5 = (const float*)d_in[14];
    const float* W6 = (const float*)d_in[15]; const float* b6 = (const float*)d_in[16];
    float* out = (float*)d_out;

    float* ws = (float*)d_ws;
    float* base = ws;                                                   // 131072 f
    unsigned short* wsT = (unsigned short*)(base + NB * NBETA * NHID);  // 49152 bf16

    hipLaunchKernelGGL(k_base_wt, dim3(256), dim3(512), 0, stream,
                       x, ei, SCB, elen, blen, W1, b1, W2, b2, W3, b3, W4, W5, W6, base, wsT);
    hipLaunchKernelGGL(k_fused, dim3(512), dim3(512), 0, stream,
                       x, ei, SCB, elen, blen, W3, base, wsT, b4, b5, b6, out);
}